// Round 1
// baseline (615.247 us; speedup 1.0000x reference)
//
#include <hip/hip_runtime.h>
#include <hip/hip_bf16.h>

typedef unsigned short u16;
typedef unsigned int u32;
typedef short bf16x8 __attribute__((ext_vector_type(8)));
typedef float f32x4 __attribute__((ext_vector_type(4)));

#define NTOK 8192
#define HID 768
#define INTER 2048
#define NEXP 8

#define MFMA16(a, b, c) __builtin_amdgcn_mfma_f32_16x16x32_bf16(a, b, c, 0, 0, 0)

__device__ __forceinline__ u16 f2bf(float f) {
    u32 u = __builtin_bit_cast(u32, f);
    u32 r = (u + 0x7FFFu + ((u >> 16) & 1u)) >> 16;
    return (u16)r;
}

__device__ __forceinline__ void gld16(const void* g, const void* l) {
    __builtin_amdgcn_global_load_lds((const __attribute__((address_space(1))) void*)g,
                                     (__attribute__((address_space(3))) void*)l, 16, 0, 0);
}

// ---------------- zero out + counts ----------------
__global__ __launch_bounds__(256) void zero_kernel(float4* out4, int n4, int* counts) {
    int i = blockIdx.x * blockDim.x + threadIdx.x;
    if (i < NEXP) counts[i] = 0;
    float4 z = {0.f, 0.f, 0.f, 0.f};
    int stride = gridDim.x * blockDim.x;
    for (int k = i; k < n4; k += stride) out4[k] = z;
}

// ---------------- fp32 -> bf16 convert (8 elems/iter) ----------------
__global__ __launch_bounds__(256) void cvt_kernel(const float* __restrict__ src, u16* __restrict__ dst, int n8) {
    int i = blockIdx.x * blockDim.x + threadIdx.x;
    int stride = gridDim.x * blockDim.x;
    for (; i < n8; i += stride) {
        const float4* s = (const float4*)(src + (size_t)i * 8);
        float4 a = s[0], b = s[1];
        u16 r[8] = {f2bf(a.x), f2bf(a.y), f2bf(a.z), f2bf(a.w),
                    f2bf(b.x), f2bf(b.y), f2bf(b.z), f2bf(b.w)};
        *(uint4*)(dst + (size_t)i * 8) = *(const uint4*)r;
    }
}

// ---------------- router: logits, top-2, softmax, scatter ----------------
__global__ __launch_bounds__(256) void router_kernel(const float* __restrict__ x, const float* __restrict__ rw,
                                                     int* counts, int* tokslot, float* wlist) {
    int wv = threadIdx.x >> 6, ln = threadIdx.x & 63;
    int t = blockIdx.x * 4 + wv;
    if (t >= NTOK) return;
    float xr[12];
#pragma unroll
    for (int j = 0; j < 12; j++) xr[j] = x[(size_t)t * HID + ln + j * 64];
    float lg[NEXP];
#pragma unroll
    for (int e = 0; e < NEXP; e++) {
        float a = 0.f;
#pragma unroll
        for (int j = 0; j < 12; j++) a += xr[j] * rw[e * HID + ln + j * 64];
#pragma unroll
        for (int off = 32; off; off >>= 1) a += __shfl_xor(a, off);
        lg[e] = a;
    }
    // top-2, lowest index wins ties (matches lax.top_k)
    int i0 = 0;
    float v0 = lg[0];
#pragma unroll
    for (int e = 1; e < NEXP; e++)
        if (lg[e] > v0) { v0 = lg[e]; i0 = e; }
    int i1 = -1;
    float v1 = -1e30f;
#pragma unroll
    for (int e = 0; e < NEXP; e++) {
        if (e == i0) continue;
        if (lg[e] > v1) { v1 = lg[e]; i1 = e; }
    }
    float w0 = 1.f / (1.f + __expf(v1 - v0));
    float w1 = 1.f - w0;
    if (ln == 0) {
        int p0 = atomicAdd(&counts[i0], 1);
        tokslot[i0 * NTOK + p0] = t;  // slot 0
        wlist[i0 * NTOK + p0] = w0;
        int p1 = atomicAdd(&counts[i1], 1);
        tokslot[i1 * NTOK + p1] = t | (1 << 16);  // slot 1
        wlist[i1 * NTOK + p1] = w1;
    }
}

// ---------------- gate_up GEMM + swiglu -> h ----------------
// grid (64 row-tiles, 32 col-tiles of 64 h-cols, 8 experts), 256 thr
__global__ __launch_bounds__(256, 2) void gateup_kernel(const u16* __restrict__ xb, const u16* __restrict__ gub,
                                                        const int* __restrict__ counts,
                                                        const int* __restrict__ tokslot, u16* __restrict__ h) {
    int e = blockIdx.z;
    int cnt = counts[e];
    int row0 = blockIdx.x * 128;
    if (row0 >= cnt) return;
    int n0 = blockIdx.y * 64;

    __shared__ u16 smem[2][2][4096];  // [buf][A/B][128*32]
    int tid = threadIdx.x, wv = tid >> 6, ln = tid & 63;

    // staging source bases (fixed per thread; add s*64 bytes each K-step)
    const char* xbB = (const char*)xb;
    const char* guB = (const char*)gub;
    const char* aSrc0;
    const char* aSrc1;
    const char* bSrc0;
    const char* bSrc1;
    {
        int o0 = (wv * 2 + 0) * 1024 + ln * 16;
        int o1 = (wv * 2 + 1) * 1024 + ln * 16;
        int r0 = o0 >> 6, kb0 = o0 & 63;
        int r1 = o1 >> 6, kb1 = o1 & 63;
        int gr0 = row0 + r0, gr1 = row0 + r1;
        int ts0 = tokslot[e * NTOK + (gr0 < cnt ? gr0 : 0)];
        int ts1 = tokslot[e * NTOK + (gr1 < cnt ? gr1 : 0)];
        aSrc0 = xbB + (size_t)(ts0 & 0xFFFF) * (HID * 2) + kb0;
        aSrc1 = xbB + (size_t)(ts1 & 0xFFFF) * (HID * 2) + kb1;
        int g0 = (r0 < 64) ? (n0 + r0) : (2048 + n0 + r0 - 64);
        int g1 = (r1 < 64) ? (n0 + r1) : (2048 + n0 + r1 - 64);
        bSrc0 = guB + ((size_t)e * 4096 + g0) * (HID * 2) + kb0;
        bSrc1 = guB + ((size_t)e * 4096 + g1) * (HID * 2) + kb1;
    }

    f32x4 acc[2][8];
#pragma unroll
    for (int m = 0; m < 2; m++)
#pragma unroll
        for (int n = 0; n < 8; n++) acc[m][n] = (f32x4)0.f;

    const int nK = HID / 32;  // 24
    int rsel = ln & 15, kg = (ln >> 4) * 8;

#define GU_STAGE(buf, s)                                                      \
    do {                                                                      \
        int off = (s)*64;                                                     \
        gld16(aSrc0 + off, &smem[buf][0][(wv * 2 + 0) * 512]);                \
        gld16(aSrc1 + off, &smem[buf][0][(wv * 2 + 1) * 512]);                \
        gld16(bSrc0 + off, &smem[buf][1][(wv * 2 + 0) * 512]);                \
        gld16(bSrc1 + off, &smem[buf][1][(wv * 2 + 1) * 512]);                \
    } while (0)

#define GU_COMPUTE(buf)                                                       \
    do {                                                                      \
        const u16* As = &smem[buf][0][0];                                     \
        const u16* Bs = &smem[buf][1][0];                                     \
        bf16x8 af[2], bfr[8];                                                 \
        _Pragma("unroll") for (int m = 0; m < 2; m++)                         \
            af[m] = *(const bf16x8*)(As + (wv * 32 + m * 16 + rsel) * 32 + kg); \
        _Pragma("unroll") for (int n = 0; n < 8; n++)                         \
            bfr[n] = *(const bf16x8*)(Bs + (n * 16 + rsel) * 32 + kg);        \
        _Pragma("unroll") for (int m = 0; m < 2; m++)                         \
            _Pragma("unroll") for (int n = 0; n < 8; n++)                     \
                acc[m][n] = MFMA16(af[m], bfr[n], acc[m][n]);                 \
    } while (0)

    GU_STAGE(0, 0);
    __syncthreads();
    int cur = 0;
    for (int s = 1; s < nK; ++s) {
        GU_STAGE(cur ^ 1, s);
        GU_COMPUTE(cur);
        __syncthreads();
        cur ^= 1;
    }
    GU_COMPUTE(cur);

    // epilogue: pair gate (frags 0..3) with up (frags 4..7), swiglu, store h
    int rg = ln >> 4;
#pragma unroll
    for (int m = 0; m < 2; m++) {
#pragma unroll
        for (int j = 0; j < 4; j++) {
            int r = wv * 32 + m * 16 + rg * 4 + j;
            int gr = row0 + r;
            if (gr >= cnt) continue;
            int ts = tokslot[e * NTOK + gr];
            int tok = ts & 0xFFFF, slot = ts >> 16;
            u16* hrow = h + (size_t)(slot * NTOK + tok) * INTER + n0;
#pragma unroll
            for (int q = 0; q < 4; q++) {
                float g = acc[m][q][j];
                float u = acc[m][q + 4][j];
                u = fminf(u, 7.0f);
                float sg = g / (1.0f + __expf(-g));
                hrow[q * 16 + rsel] = f2bf(sg * u);
            }
        }
    }
#undef GU_STAGE
#undef GU_COMPUTE
}

// ---------------- down GEMM + weighted scatter-add ----------------
// grid (64 row-tiles, 6 col-tiles of 128, 8 experts), 256 thr
__global__ __launch_bounds__(256, 2) void down_kernel(const u16* __restrict__ hb, const u16* __restrict__ dnb,
                                                      const int* __restrict__ counts,
                                                      const int* __restrict__ tokslot,
                                                      const float* __restrict__ wlist, float* __restrict__ out) {
    int e = blockIdx.z;
    int cnt = counts[e];
    int row0 = blockIdx.x * 128;
    if (row0 >= cnt) return;
    int col0 = blockIdx.y * 128;

    __shared__ u16 smem[2][2][4096];
    int tid = threadIdx.x, wv = tid >> 6, ln = tid & 63;

    const char* hbB = (const char*)hb;
    const char* dnB = (const char*)dnb;
    const char* aSrc0;
    const char* aSrc1;
    const char* bSrc0;
    const char* bSrc1;
    {
        int o0 = (wv * 2 + 0) * 1024 + ln * 16;
        int o1 = (wv * 2 + 1) * 1024 + ln * 16;
        int r0 = o0 >> 6, kb0 = o0 & 63;
        int r1 = o1 >> 6, kb1 = o1 & 63;
        int gr0 = row0 + r0, gr1 = row0 + r1;
        int ts0 = tokslot[e * NTOK + (gr0 < cnt ? gr0 : 0)];
        int ts1 = tokslot[e * NTOK + (gr1 < cnt ? gr1 : 0)];
        aSrc0 = hbB + (size_t)((ts0 >> 16) * NTOK + (ts0 & 0xFFFF)) * (INTER * 2) + kb0;
        aSrc1 = hbB + (size_t)((ts1 >> 16) * NTOK + (ts1 & 0xFFFF)) * (INTER * 2) + kb1;
        bSrc0 = dnB + ((size_t)e * HID + col0 + r0) * (INTER * 2) + kb0;
        bSrc1 = dnB + ((size_t)e * HID + col0 + r1) * (INTER * 2) + kb1;
    }

    f32x4 acc[4][4];
#pragma unroll
    for (int m = 0; m < 4; m++)
#pragma unroll
        for (int n = 0; n < 4; n++) acc[m][n] = (f32x4)0.f;

    const int nK = INTER / 32;  // 64
    int rsel = ln & 15, kg = (ln >> 4) * 8;
    int wr = wv >> 1, wc = wv & 1;

#define DN_STAGE(buf, s)                                                      \
    do {                                                                      \
        int off = (s)*64;                                                     \
        gld16(aSrc0 + off, &smem[buf][0][(wv * 2 + 0) * 512]);                \
        gld16(aSrc1 + off, &smem[buf][0][(wv * 2 + 1) * 512]);                \
        gld16(bSrc0 + off, &smem[buf][1][(wv * 2 + 0) * 512]);                \
        gld16(bSrc1 + off, &smem[buf][1][(wv * 2 + 1) * 512]);                \
    } while (0)

#define DN_COMPUTE(buf)                                                       \
    do {                                                                      \
        const u16* As = &smem[buf][0][0];                                     \
        const u16* Bs = &smem[buf][1][0];                                     \
        bf16x8 af[4], bfr[4];                                                 \
        _Pragma("unroll") for (int m = 0; m < 4; m++)                         \
            af[m] = *(const bf16x8*)(As + (wr * 64 + m * 16 + rsel) * 32 + kg); \
        _Pragma("unroll") for (int n = 0; n < 4; n++)                         \
            bfr[n] = *(const bf16x8*)(Bs + (wc * 64 + n * 16 + rsel) * 32 + kg); \
        _Pragma("unroll") for (int m = 0; m < 4; m++)                         \
            _Pragma("unroll") for (int n = 0; n < 4; n++)                     \
                acc[m][n] = MFMA16(af[m], bfr[n], acc[m][n]);                 \
    } while (0)

    DN_STAGE(0, 0);
    __syncthreads();
    int cur = 0;
    for (int s = 1; s < nK; ++s) {
        DN_STAGE(cur ^ 1, s);
        DN_COMPUTE(cur);
        __syncthreads();
        cur ^= 1;
    }
    DN_COMPUTE(cur);

    int rg = ln >> 4;
#pragma unroll
    for (int m = 0; m < 4; m++) {
#pragma unroll
        for (int j = 0; j < 4; j++) {
            int r = wr * 64 + m * 16 + rg * 4 + j;
            int gr = row0 + r;
            if (gr >= cnt) continue;
            int ts = tokslot[e * NTOK + gr];
            int tok = ts & 0xFFFF;
            float w = wlist[e * NTOK + gr];
#pragma unroll
            for (int n = 0; n < 4; n++) {
                int col = col0 + wc * 64 + n * 16 + rsel;
                atomicAdd(&out[(size_t)tok * HID + col], w * acc[m][n][j]);
            }
        }
    }
#undef DN_STAGE
#undef DN_COMPUTE
}

// ---------------- launch ----------------
extern "C" void kernel_launch(void* const* d_in, const int* in_sizes, int n_in,
                              void* d_out, int out_size, void* d_ws, size_t ws_size,
                              hipStream_t stream) {
    const float* x = (const float*)d_in[0];
    const float* rw = (const float*)d_in[1];
    const float* gu = (const float*)d_in[2];
    const float* dn = (const float*)d_in[3];
    float* out = (float*)d_out;
    char* ws = (char*)d_ws;

    // workspace layout (bytes)
    int* counts = (int*)(ws + 0);                 // 256
    int* tokslot = (int*)(ws + 256);              // 8*8192*4 = 262144
    float* wlist = (float*)(ws + 262400);         // 262144
    u16* xb = (u16*)(ws + 524544);                // 8192*768*2   = 12582912
    u16* gub = (u16*)(ws + 13107456);             // 8*4096*768*2 = 50331648
    u16* dnb = (u16*)(ws + 63439104);             // 8*768*2048*2 = 25165824
    u16* hb = (u16*)(ws + 88604928);              // 16384*2048*2 = 67108864
    // total = 155713792 bytes

    zero_kernel<<<1024, 256, 0, stream>>>((float4*)out, NTOK * HID / 4, counts);
    cvt_kernel<<<2048, 256, 0, stream>>>(x, xb, NTOK * HID / 8);
    cvt_kernel<<<2048, 256, 0, stream>>>(gu, gub, NEXP * 2 * INTER * HID / 8);
    cvt_kernel<<<2048, 256, 0, stream>>>(dn, dnb, NEXP * HID * INTER / 8);
    router_kernel<<<NTOK / 4, 256, 0, stream>>>(x, rw, counts, tokslot, wlist);
    gateup_kernel<<<dim3(64, 32, 8), 256, 0, stream>>>(xb, gub, counts, tokslot, hb);
    down_kernel<<<dim3(64, 6, 8), 256, 0, stream>>>(hb, dnb, counts, tokslot, wlist, out);
}